// Round 1
// baseline (197.459 us; speedup 1.0000x reference)
//
#include <hip/hip_runtime.h>
#include <stdint.h>

// BinaryBoundarySoftDice on MI355X.
// Key identity: sum_{k=0..20} dilate^k(edge) per pixel = max(0, 21 - d0) where
// d0 = Chebyshev distance to nearest edge pixel within the (b,d) slice.
// => dist = (min(d0,21)+1)/22, weight = 2/(1+exp(10*dist)) -- only 22 values.
// One block per slice: bitwise dilation on 256x256 bitmask, record first-set
// iteration per pixel, then one coalesced weighted-reduction pass.

__global__ __launch_bounds__(256) void bbsd_main(const float* __restrict__ outputs,
                                                 const int* __restrict__ masks,
                                                 float* __restrict__ acc) {
    __shared__ unsigned long long mbits[256][4];  // mask bits, row-major, bit c&63 of word c>>6
    __shared__ unsigned long long tmpb[256][4];   // horizontally-dilated rows
    __shared__ unsigned char d0buf[256 * 256];    // first-set iteration per pixel (255 = never)
    __shared__ float wtab[22];

    const int t = threadIdx.x;       // 0..255
    const int lane = t & 63;
    const int wv = t >> 6;           // wave id 0..3
    const int slice = blockIdx.x;    // 0..127 (b*64 + d)
    const int b = slice >> 6;
    const size_t base = (size_t)slice * 65536;

    // init d0buf row t to 255 (never set)
    {
        unsigned long long* p = (unsigned long long*)(d0buf + t * 256);
        #pragma unroll
        for (int j = 0; j < 32; ++j) p[j] = 0xFFFFFFFFFFFFFFFFull;
    }
    if (t < 22) {
        float dist = (float)(t + 1) * (1.0f / 22.0f);
        wtab[t] = 2.0f / (1.0f + __expf(10.0f * dist));
    }

    // ---- phase 1: build mask bitmap (coalesced loads + wave ballot) ----
    for (int i = 0; i < 256; ++i) {
        int v = masks[base + (size_t)i * 256 + t];
        unsigned long long bal = __ballot(v != 0);
        if (lane == 0) mbits[i][wv] = bal;
    }
    __syncthreads();

    // ---- phase 2: edge map for row y = t ----
    // edge = m==1 AND at least one 4-neighbor (zero-padded) is 0
    unsigned long long c[4];
    {
        const int y = t;
        unsigned long long m[4], up[4], dn[4];
        #pragma unroll
        for (int j = 0; j < 4; ++j) {
            m[j]  = mbits[y][j];
            up[j] = (y > 0)   ? mbits[y - 1][j] : 0ull;
            dn[j] = (y < 255) ? mbits[y + 1][j] : 0ull;
        }
        #pragma unroll
        for (int j = 0; j < 4; ++j) {
            unsigned long long lf = (m[j] << 1) | (j > 0 ? (m[j - 1] >> 63) : 0ull);
            unsigned long long rt = (m[j] >> 1) | (j < 3 ? (m[j + 1] << 63) : 0ull);
            c[j] = m[j] & ~(up[j] & dn[j] & lf & rt);
        }
        // record d0 = 0 for edge pixels
        #pragma unroll
        for (int j = 0; j < 4; ++j) {
            unsigned long long nw = c[j];
            while (nw) {
                int bp = __builtin_ctzll(nw);
                nw &= nw - 1;
                d0buf[y * 256 + j * 64 + bp] = 0;
            }
        }
    }
    __syncthreads();

    // ---- phase 3: up to 20 bitwise 3x3 dilations, record first-set iteration ----
    for (int k = 1; k <= 20; ++k) {
        unsigned long long h[4];
        #pragma unroll
        for (int j = 0; j < 4; ++j) {
            unsigned long long lf = (c[j] << 1) | (j > 0 ? (c[j - 1] >> 63) : 0ull);
            unsigned long long rt = (c[j] >> 1) | (j < 3 ? (c[j + 1] << 63) : 0ull);
            h[j] = c[j] | lf | rt;
            tmpb[t][j] = h[j];
        }
        __syncthreads();
        const int y = t;
        #pragma unroll
        for (int j = 0; j < 4; ++j) {
            unsigned long long up = (y > 0)   ? tmpb[y - 1][j] : 0ull;
            unsigned long long dn = (y < 255) ? tmpb[y + 1][j] : 0ull;
            unsigned long long n = h[j] | up | dn;
            unsigned long long nw = n & ~c[j];
            c[j] = n;
            while (nw) {
                int bp = __builtin_ctzll(nw);
                nw &= nw - 1;
                d0buf[y * 256 + j * 64 + bp] = (unsigned char)k;
            }
        }
        // early exit when the whole slice is saturated (no future new bits)
        int done = ((c[0] & c[1] & c[2] & c[3]) == 0xFFFFFFFFFFFFFFFFull) ? 1 : 0;
        if (__syncthreads_and(done)) break;
    }
    __syncthreads();

    // ---- phase 4: coalesced weighted reduction ----
    float s_ow = 0.0f, s_mw = 0.0f, s_owm = 0.0f;
    for (int i = 0; i < 256; ++i) {
        float ov = outputs[base + (size_t)i * 256 + t];
        int mbit = (int)((mbits[i][wv] >> lane) & 1ull);
        int d0 = (int)d0buf[i * 256 + t];
        float w = wtab[d0 < 22 ? d0 : 21];
        float ow = ov * w;
        s_ow += ow;
        if (mbit) { s_mw += w; s_owm += ow; }
    }
    #pragma unroll
    for (int off = 32; off > 0; off >>= 1) {
        s_ow  += __shfl_down(s_ow, off);
        s_mw  += __shfl_down(s_mw, off);
        s_owm += __shfl_down(s_owm, off);
    }
    if (lane == 0) {
        atomicAdd(&acc[b * 3 + 0], s_ow);
        atomicAdd(&acc[b * 3 + 1], s_mw);
        atomicAdd(&acc[b * 3 + 2], s_owm);
    }
}

__global__ void bbsd_fin(const float* __restrict__ acc, float* __restrict__ out) {
    float loss = 0.0f;
    #pragma unroll
    for (int b = 0; b < 2; ++b) {
        float A = acc[b * 3 + 0];   // input_area  = sum(outputs*weight)
        float T = acc[b * 3 + 1];   // target_area = sum(m*weight)
        float I = acc[b * 3 + 2];   // intersect   = sum(outputs*weight*m)
        float l = (T == 0.0f) ? 0.0f : (1.0f - 2.0f * I / (A + T + 2e-6f));
        loss += l;
    }
    out[0] = 0.5f * loss;
}

extern "C" void kernel_launch(void* const* d_in, const int* in_sizes, int n_in,
                              void* d_out, int out_size, void* d_ws, size_t ws_size,
                              hipStream_t stream) {
    const float* outputs = (const float*)d_in[0];
    const int* masks = (const int*)d_in[1];
    float* out = (float*)d_out;
    float* acc = (float*)d_ws;

    hipMemsetAsync(acc, 0, 6 * sizeof(float), stream);
    bbsd_main<<<128, 256, 0, stream>>>(outputs, masks, acc);
    bbsd_fin<<<1, 1, 0, stream>>>(acc, out);
}

// Round 2
// 114.983 us; speedup vs baseline: 1.7173x; 1.7173x over previous
//
#include <hip/hip_runtime.h>
#include <stdint.h>

typedef unsigned long long u64;

// Geometry: 2 batches x 64 depth slices x 256 x 256. 128 slices total.
#define SLICES 128
#define WPS 1024                    // 64-bit words per slice (65536/64)
#define TOTAL_WORDS (SLICES * WPS)  // 131072 words = 1 MB
#define NBLK3 512                   // blocks for the reduction kernel

// ws layout (u64 words):
//   [0, 131072)              mask bitmap (bit = pixel, global word idx = pix>>6)
//   [131072*(1+pl), ...)     plane pl, pl = 0..4  (d0 value bit-planes)
// partials (float): byte offset 6*131072*8, NBLK3*6 floats.
// Total ~6.3 MB of d_ws. Everything read is fully written each call (poison-safe).

// ---- kernel 1: pack masks into a bitmask via wave ballot ----
__global__ __launch_bounds__(256) void k_pack(const int* __restrict__ masks,
                                              u64* __restrict__ mbits) {
    const int lane = threadIdx.x & 63;
    const int wave = (blockIdx.x * 256 + threadIdx.x) >> 6;
    const int nwaves = (gridDim.x * 256) >> 6;
    #pragma unroll 4
    for (int w = wave; w < TOTAL_WORDS; w += nwaves) {
        int v = masks[(size_t)w * 64 + lane];
        u64 bal = __ballot(v != 0);
        if (lane == 0) mbits[w] = bal;
    }
}

// ---- kernel 2: edge + cascaded 3x3 dilation, d0 recorded as 5 bit-planes ----
__global__ __launch_bounds__(256) void k_dilate(const u64* __restrict__ mbits,
                                                u64* __restrict__ planes) {
    __shared__ u64 rows[256][5];  // +1 word pad to break bank alignment
    __shared__ u64 tmp[256][5];

    const int t = threadIdx.x;       // row this thread owns
    const int slice = blockIdx.x;
    const u64* mb = mbits + (size_t)slice * WPS;

    u64 m[4];
    #pragma unroll
    for (int j = 0; j < 4; ++j) { m[j] = mb[t * 4 + j]; rows[t][j] = m[j]; }
    __syncthreads();

    // edge = m & ~(up & dn & lf & rt), zero-padded borders
    u64 c[4];
    {
        u64 up[4], dn[4];
        #pragma unroll
        for (int j = 0; j < 4; ++j) {
            up[j] = (t > 0)   ? rows[t - 1][j] : 0ull;
            dn[j] = (t < 255) ? rows[t + 1][j] : 0ull;
        }
        #pragma unroll
        for (int j = 0; j < 4; ++j) {
            u64 lf = (m[j] << 1) | (j > 0 ? (m[j - 1] >> 63) : 0ull);
            u64 rt = (m[j] >> 1) | (j < 3 ? (m[j + 1] << 63) : 0ull);
            c[j] = m[j] & ~(up[j] & dn[j] & lf & rt);
        }
    }

    u64 p[5][4];
    #pragma unroll
    for (int pl = 0; pl < 5; ++pl)
        #pragma unroll
        for (int j = 0; j < 4; ++j) p[pl][j] = 0ull;

    __syncthreads();  // rows reads done before tmp-phase (tmp separate; this guards nothing heavy)

    for (int k = 1; k <= 20; ++k) {
        u64 h[4];
        #pragma unroll
        for (int j = 0; j < 4; ++j) {
            u64 lf = (c[j] << 1) | (j > 0 ? (c[j - 1] >> 63) : 0ull);
            u64 rt = (c[j] >> 1) | (j < 3 ? (c[j + 1] << 63) : 0ull);
            h[j] = c[j] | lf | rt;
            tmp[t][j] = h[j];
        }
        __syncthreads();
        #pragma unroll
        for (int j = 0; j < 4; ++j) {
            u64 u_ = (t > 0)   ? tmp[t - 1][j] : 0ull;
            u64 d_ = (t < 255) ? tmp[t + 1][j] : 0ull;
            u64 n = h[j] | u_ | d_;
            u64 nw = n & ~c[j];
            c[j] = n;
            #pragma unroll
            for (int pl = 0; pl < 5; ++pl)
                if ((k >> pl) & 1) p[pl][j] |= nw;
        }
        int done = ((c[0] & c[1] & c[2] & c[3]) == 0xFFFFFFFFFFFFFFFFull) ? 1 : 0;
        if (__syncthreads_and(done)) break;  // barrier: protects tmp reuse next iter
    }

    // never-covered pixels encode d0 = 21 (0b10101)
    #pragma unroll
    for (int j = 0; j < 4; ++j) {
        u64 u_ = ~c[j];
        p[0][j] |= u_; p[2][j] |= u_; p[4][j] |= u_;
    }

    #pragma unroll
    for (int pl = 0; pl < 5; ++pl)
        #pragma unroll
        for (int j = 0; j < 4; ++j)
            planes[(size_t)pl * TOTAL_WORDS + (size_t)slice * WPS + t * 4 + j] = p[pl][j];
}

// ---- kernel 3: weighted reduction over outputs ----
__global__ __launch_bounds__(256) void k_reduce(const float* __restrict__ outputs,
                                               const u64* __restrict__ mbits,
                                               const u64* __restrict__ planes,
                                               float* __restrict__ partials) {
    __shared__ float wtab[22];
    __shared__ float red[4][6];
    const int t = threadIdx.x;
    if (t < 22) wtab[t] = 2.0f / (1.0f + __expf(10.0f * (float)(t + 1) * (1.0f / 22.0f)));
    __syncthreads();

    const int tid = blockIdx.x * 256 + t;  // 0..131071
    float s[2][3];
    #pragma unroll
    for (int b = 0; b < 2; ++b) { s[b][0] = s[b][1] = s[b][2] = 0.0f; }

    #pragma unroll
    for (int b = 0; b < 2; ++b) {
        for (int i = 0; i < 8; ++i) {
            int pix4 = b * 1048576 + i * 131072 + tid;
            int pix = pix4 * 4;           // fits: < 8.4M
            float4 o4 = ((const float4*)outputs)[pix4];
            float ov[4] = {o4.x, o4.y, o4.z, o4.w};
            int widx = pix >> 6;
            int sh = pix & 63;
            u64 mw = mbits[widx];
            u64 p0 = planes[widx];
            u64 p1 = planes[TOTAL_WORDS + widx];
            u64 p2 = planes[2 * TOTAL_WORDS + widx];
            u64 p3 = planes[3 * TOTAL_WORDS + widx];
            u64 p4 = planes[4 * TOTAL_WORDS + widx];
            #pragma unroll
            for (int q = 0; q < 4; ++q) {
                int s2 = sh + q;
                int d0 = (int)((p0 >> s2) & 1ull)
                       | ((int)((p1 >> s2) & 1ull) << 1)
                       | ((int)((p2 >> s2) & 1ull) << 2)
                       | ((int)((p3 >> s2) & 1ull) << 3)
                       | ((int)((p4 >> s2) & 1ull) << 4);
                float w = wtab[d0];
                float ow = ov[q] * w;
                s[b][0] += ow;
                if ((mw >> s2) & 1ull) { s[b][1] += w; s[b][2] += ow; }
            }
        }
    }

    // wave reduce 6 values
    #pragma unroll
    for (int b = 0; b < 2; ++b)
        #pragma unroll
        for (int k = 0; k < 3; ++k) {
            float v = s[b][k];
            #pragma unroll
            for (int off = 32; off > 0; off >>= 1) v += __shfl_down(v, off);
            s[b][k] = v;
        }
    const int lane = t & 63, wv = t >> 6;
    if (lane == 0) {
        #pragma unroll
        for (int b = 0; b < 2; ++b)
            #pragma unroll
            for (int k = 0; k < 3; ++k) red[wv][b * 3 + k] = s[b][k];
    }
    __syncthreads();
    if (t < 6) {
        float v = red[0][t] + red[1][t] + red[2][t] + red[3][t];
        partials[blockIdx.x * 6 + t] = v;
    }
}

// ---- kernel 4: final reduce + dice ----
__global__ __launch_bounds__(64) void k_fin(const float* __restrict__ partials,
                                            float* __restrict__ out) {
    const int lane = threadIdx.x;
    float s[6] = {0, 0, 0, 0, 0, 0};
    for (int i = lane; i < NBLK3; i += 64)
        #pragma unroll
        for (int k = 0; k < 6; ++k) s[k] += partials[i * 6 + k];
    #pragma unroll
    for (int k = 0; k < 6; ++k) {
        float v = s[k];
        #pragma unroll
        for (int off = 32; off > 0; off >>= 1) v += __shfl_down(v, off);
        s[k] = v;
    }
    if (lane == 0) {
        float loss = 0.0f;
        #pragma unroll
        for (int b = 0; b < 2; ++b) {
            float A = s[b * 3 + 0];   // sum(outputs*w)
            float T = s[b * 3 + 1];   // sum(m*w)
            float I = s[b * 3 + 2];   // sum(outputs*w*m)
            float l = (T == 0.0f) ? 0.0f : (1.0f - 2.0f * I / (A + T + 2e-6f));
            loss += l;
        }
        out[0] = 0.5f * loss;
    }
}

extern "C" void kernel_launch(void* const* d_in, const int* in_sizes, int n_in,
                              void* d_out, int out_size, void* d_ws, size_t ws_size,
                              hipStream_t stream) {
    const float* outputs = (const float*)d_in[0];
    const int* masks = (const int*)d_in[1];
    float* out = (float*)d_out;

    u64* mbits = (u64*)d_ws;
    u64* planes = mbits + TOTAL_WORDS;
    float* partials = (float*)((char*)d_ws + (size_t)6 * TOTAL_WORDS * 8);

    k_pack<<<1024, 256, 0, stream>>>(masks, mbits);
    k_dilate<<<SLICES, 256, 0, stream>>>(mbits, planes);
    k_reduce<<<NBLK3, 256, 0, stream>>>(outputs, mbits, planes, partials);
    k_fin<<<1, 64, 0, stream>>>(partials, out);
}